// Round 4
// baseline (140.556 us; speedup 1.0000x reference)
//
#include <hip/hip_runtime.h>
#include <stdint.h>

#define BB 16
#define NN 2048
#define DD 64
#define BN 64
#define KSTR 72   // K LDS row stride (bf16 elems): 36 words -> uniform bank coverage for b128
#define VSTR 72
#define PSTR 72

typedef __attribute__((ext_vector_type(8))) short short8;
typedef __attribute__((ext_vector_type(16))) float f32x16;

__device__ __forceinline__ unsigned short f2bf(float f) {   // RNE (prep)
  union { float f; uint32_t u; } c; c.f = f;
  uint32_t u = c.u + 0x7fffu + ((c.u >> 16) & 1u);
  return (unsigned short)(u >> 16);
}
__device__ __forceinline__ uint32_t pk2(float a, float b) {  // round-half-up bf16x2 pack
  union { float f; uint32_t u; } x, y; x.f = a; y.f = b;
  return ((x.u + 0x8000u) >> 16) | ((y.u + 0x8000u) & 0xffff0000u);
}

// ---- pre-pass: V fp32 [b][key][d] -> bf16 transposed vt [b][d][key] (round-2 verified) ----
__global__ __launch_bounds__(256) void prep_kernel(const float* __restrict__ v,
                                                   unsigned short* __restrict__ vt) {
  __shared__ float t[64][65];
  int bid = blockIdx.x, tid = threadIdx.x;
  int b = bid >> 5;
  int k0 = (bid & 31) * 64;
  const float4* src = (const float4*)(v + ((size_t)b * NN + k0) * DD);
#pragma unroll
  for (int i = 0; i < 4; i++) {
    int f4 = tid + i * 256;
    int row = f4 >> 4, c4 = f4 & 15;
    float4 f = src[f4];
    t[row][c4*4+0] = f.x; t[row][c4*4+1] = f.y; t[row][c4*4+2] = f.z; t[row][c4*4+3] = f.w;
  }
  __syncthreads();
  int d = tid >> 2, kg = tid & 3;
  unsigned short* dst = vt + ((size_t)b * DD + d) * NN + k0 + kg * 16;
#pragma unroll
  for (int u = 0; u < 4; u++) {
    ushort4 o4;
    o4.x = f2bf(t[kg*16+u*4+0][d]);
    o4.y = f2bf(t[kg*16+u*4+1][d]);
    o4.z = f2bf(t[kg*16+u*4+2][d]);
    o4.w = f2bf(t[kg*16+u*4+3][d]);
    ((ushort4*)dst)[u] = o4;
  }
}

// ---- main attention: 32x32x16 MFMA, S^T orientation, 2 waves x 64 queries, BN=64 ----
template <int NS>
__global__ __launch_bounds__(128, 2) void attn_kernel(
    const float* __restrict__ q, const float* __restrict__ kin,
    const unsigned short* __restrict__ vtbf, const int* __restrict__ valid,
    float* __restrict__ out, unsigned short* __restrict__ po,
    float* __restrict__ pz)
{
  constexpr int JLEN = NN / NS;
  constexpr int ITERS = JLEN / BN;

  __shared__ __align__(16) unsigned short Klds[BN * KSTR];       //  9216 B (64 keys x 64 d)
  __shared__ __align__(16) unsigned short Vlds[DD * VSTR];       //  9216 B (64 d x 64 keys)
  __shared__ __align__(16) unsigned short Plds[2 * 64 * PSTR];   // 18432 B (2 waves x 64 q x 64 k)

  // decode: id&7 = XCD (RR dispatch), 2 batches/XCD for K/V L2 residency
  int id = blockIdx.x;
  int b = (id & 7) + 8 * ((id >> 3) & 1);
  int r2 = id >> 4;
  int sp = r2 % NS;
  int qt = r2 / NS;
  int i0 = qt * 128;                    // block owns 128 queries
  int jbase = sp * JLEN;

  int tid = threadIdx.x;
  int w = tid >> 6;                     // wave 0/1: queries i0 + w*64 .. +63
  int lane = tid & 63;
  int q32 = lane & 31;                  // MFMA row/col lane field
  int h = lane >> 5;                    // k-group half

  // per-lane valid[] for this lane's two query columns (u=0,1)
  int vq[2];
#pragma unroll
  for (int u = 0; u < 2; u++)
    vq[u] = valid[b * NN + i0 + w * 64 + u * 32 + q32];

  // Q B-fragments: B[col=u*32+q32][k=ds*16+h*8+j], scale 0.125 folded, fp32->bf16
  short8 qf[2][4];
#pragma unroll
  for (int u = 0; u < 2; u++) {
    const float* qp = q + ((size_t)b * NN + (i0 + w * 64 + u * 32 + q32)) * DD;
#pragma unroll
    for (int ds = 0; ds < 4; ds++) {
      float4 f0 = *(const float4*)(qp + ds * 16 + h * 8);
      float4 f1 = *(const float4*)(qp + ds * 16 + h * 8 + 4);
      union { short8 v; uint32_t x[4]; } tmp;
      tmp.x[0] = pk2(f0.x * 0.125f, f0.y * 0.125f);
      tmp.x[1] = pk2(f0.z * 0.125f, f0.w * 0.125f);
      tmp.x[2] = pk2(f1.x * 0.125f, f1.y * 0.125f);
      tmp.x[3] = pk2(f1.z * 0.125f, f1.w * 0.125f);
      qf[u][ds] = tmp.v;
    }
  }

  f32x16 o[2][2] = {};                  // O^T accum: [dtile t][qtile u]
  float z[2] = {0.0f, 0.0f};
  unsigned short* pbase = Plds + w * 64 * PSTR;

  // staging: thread covers row tid>>1, 32-col half (tid&1)
  int srow = tid >> 1, shalf = (tid & 1) * 32;
  const float* gk = kin + ((size_t)(b * NN + jbase + srow)) * DD + shalf;          // fp32 K
  const unsigned short* gv = vtbf + ((size_t)b * DD + srow) * NN + jbase + shalf;  // bf16 Vt

  float4 kr[8]; uint4 vr[4];
#pragma unroll
  for (int i = 0; i < 8; i++) kr[i] = ((const float4*)gk)[i];
#pragma unroll
  for (int i = 0; i < 4; i++) vr[i] = ((const uint4*)gv)[i];

  const float CM = 1.0000010f;          // exp(1e-6): masked-key weight (NOT zero)

  for (int it = 0; it < ITERS; ++it) {
    int jb0 = jbase + it * BN;
    __syncthreads();                    // prior tile fully consumed
    // write staged tile (K converted fp32->bf16 here; no K pre-pass)
#pragma unroll
    for (int s = 0; s < 4; s++) {
      union { uint4 u4; uint32_t x[4]; } kw;
      kw.x[0] = pk2(kr[2*s].x, kr[2*s].y);
      kw.x[1] = pk2(kr[2*s].z, kr[2*s].w);
      kw.x[2] = pk2(kr[2*s+1].x, kr[2*s+1].y);
      kw.x[3] = pk2(kr[2*s+1].z, kr[2*s+1].w);
      *(uint4*)&Klds[srow * KSTR + shalf + s * 8] = kw.u4;
      *(uint4*)&Vlds[srow * VSTR + shalf + s * 8] = vr[s];
    }
    if (it + 1 < ITERS) {               // prefetch next tile
      gk += BN * DD; gv += BN;
#pragma unroll
      for (int i = 0; i < 8; i++) kr[i] = ((const float4*)gk)[i];
#pragma unroll
      for (int i = 0; i < 4; i++) vr[i] = ((const uint4*)gv)[i];
    }
    __syncthreads();

    // S^T = K . Q^T per 32-key subtile c; one K-frag read feeds both q-tiles
#pragma unroll
    for (int c = 0; c < 2; c++) {
      f32x16 s0 = {}, s1 = {};
#pragma unroll
      for (int ds = 0; ds < 4; ds++) {
        short8 kf = *(const short8*)&Klds[(c * 32 + q32) * KSTR + ds * 16 + h * 8];
        s0 = __builtin_amdgcn_mfma_f32_32x32x16_bf16(kf, qf[0][ds], s0, 0, 0, 0);
        s1 = __builtin_amdgcn_mfma_f32_32x32x16_bf16(kf, qf[1][ds], s1, 0, 0, 0);
      }
      // exp + mask; C/D: col=q32, row(key) = (reg&3) + 8*(reg>>2) + 4*h
#pragma unroll
      for (int u = 0; u < 2; u++) {
        const f32x16& sv = u ? s1 : s0;
#pragma unroll
        for (int g = 0; g < 4; g++) {
          float e[4];
#pragma unroll
          for (int rr = 0; rr < 4; rr++) {
            int j = jb0 + c * 32 + g * 8 + 4 * h + rr;
            float ex = __expf(sv[g * 4 + rr]);
            e[rr] = (j < vq[u]) ? ex : CM;
            z[u] += e[rr];
          }
          *(uint2*)&pbase[(u * 32 + q32) * PSTR + c * 32 + g * 8 + 4 * h] =
              make_uint2(pk2(e[0], e[1]), pk2(e[2], e[3]));
        }
      }
    }

    __builtin_amdgcn_s_waitcnt(0xc07f);  // lgkmcnt(0): wave-local P RAW

    // O^T += V^T . P^T : one V-frag feeds both q-tiles, one P-frag both d-tiles
#pragma unroll
    for (int ks = 0; ks < 4; ks++) {
      short8 vf0 = *(const short8*)&Vlds[(0 * 32 + q32) * VSTR + ks * 16 + h * 8];
      short8 vf1 = *(const short8*)&Vlds[(1 * 32 + q32) * VSTR + ks * 16 + h * 8];
      short8 pf0 = *(const short8*)&pbase[(0 * 32 + q32) * PSTR + ks * 16 + h * 8];
      short8 pf1 = *(const short8*)&pbase[(1 * 32 + q32) * PSTR + ks * 16 + h * 8];
      o[0][0] = __builtin_amdgcn_mfma_f32_32x32x16_bf16(vf0, pf0, o[0][0], 0, 0, 0);
      o[0][1] = __builtin_amdgcn_mfma_f32_32x32x16_bf16(vf0, pf1, o[0][1], 0, 0, 0);
      o[1][0] = __builtin_amdgcn_mfma_f32_32x32x16_bf16(vf1, pf0, o[1][0], 0, 0, 0);
      o[1][1] = __builtin_amdgcn_mfma_f32_32x32x16_bf16(vf1, pf1, o[1][1], 0, 0, 0);
    }
  }

  // z: other key-half lives in lane^32 (same q32)
#pragma unroll
  for (int u = 0; u < 2; u++) z[u] += __shfl_xor(z[u], 32);

  if (NS > 1) {
    // bf16 partials + z to workspace
#pragma unroll
    for (int u = 0; u < 2; u++) {
      int row = i0 + w * 64 + u * 32 + q32;
      unsigned short* op = po + ((size_t)((sp * BB + b) * NN) + row) * DD;
#pragma unroll
      for (int t = 0; t < 2; t++)
#pragma unroll
        for (int g = 0; g < 4; g++) {
          const f32x16& ov = o[t][u];
          *(uint2*)&op[t * 32 + g * 8 + 4 * h] =
              make_uint2(pk2(ov[g*4+0], ov[g*4+1]), pk2(ov[g*4+2], ov[g*4+3]));
        }
      if (h == 0) pz[(size_t)(sp * BB + b) * NN + row] = z[u];
    }
  } else {
#pragma unroll
    for (int u = 0; u < 2; u++) {
      float inv = 1.0f / z[u];
      int row = i0 + w * 64 + u * 32 + q32;
      float* op = out + ((size_t)b * NN + row) * DD;
#pragma unroll
      for (int t = 0; t < 2; t++)
#pragma unroll
        for (int g = 0; g < 4; g++) {
          const f32x16& ov = o[t][u];
          *(float4*)&op[t * 32 + g * 8 + 4 * h] =
              make_float4(ov[g*4+0]*inv, ov[g*4+1]*inv, ov[g*4+2]*inv, ov[g*4+3]*inv);
        }
    }
  }
}

// ---- combine (NS=4): out = sum_sp po / sum_sp z ----
__global__ __launch_bounds__(256) void combine_kernel(const unsigned short* __restrict__ po,
                                                      const float* __restrict__ pz,
                                                      float* __restrict__ out) {
  int gid = blockIdx.x * 256 + threadIdx.x;   // 262144 threads x 8 elems
  size_t base = (size_t)gid * 8;
  int rowz = gid >> 3;
  float r[8] = {0,0,0,0,0,0,0,0};
  float zs = 0.0f;
#pragma unroll
  for (int sp = 0; sp < 4; sp++) {
    uint4 a = *(const uint4*)(po + (size_t)sp * BB * NN * DD + base);
    zs += pz[(size_t)sp * BB * NN + rowz];
    uint32_t aw[4] = {a.x, a.y, a.z, a.w};
#pragma unroll
    for (int i = 0; i < 4; i++) {
      r[2*i]   += __uint_as_float(aw[i] << 16);
      r[2*i+1] += __uint_as_float(aw[i] & 0xffff0000u);
    }
  }
  float inv = 1.0f / zs;
  float4* op = (float4*)(out + base);
  op[0] = make_float4(r[0]*inv, r[1]*inv, r[2]*inv, r[3]*inv);
  op[1] = make_float4(r[4]*inv, r[5]*inv, r[6]*inv, r[7]*inv);
}

extern "C" void kernel_launch(void* const* d_in, const int* in_sizes, int n_in,
                              void* d_out, int out_size, void* d_ws, size_t ws_size,
                              hipStream_t stream) {
  const float* q = (const float*)d_in[0];
  const float* k = (const float*)d_in[1];
  const float* v = (const float*)d_in[2];
  const int* valid = (const int*)d_in[3];
  float* out = (float*)d_out;

  unsigned short* vtbf = (unsigned short*)d_ws;                  // 4 MB
  unsigned short* po   = vtbf + (size_t)BB * NN * DD;            // 4 x 4 MB bf16 partials
  float* pz = (float*)(po + (size_t)4 * BB * NN * DD);           // 4 x 128 KB

  size_t need = (size_t)BB * NN * DD * 2                         // vtbf
              + (size_t)4 * BB * NN * DD * 2                     // po
              + (size_t)4 * BB * NN * 4;                         // pz

  hipLaunchKernelGGL(prep_kernel, dim3(BB * (NN / 64)), dim3(256), 0, stream, v, vtbf);
  if (ws_size >= need) {
    hipLaunchKernelGGL((attn_kernel<4>), dim3(1024), dim3(128), 0, stream,
                       q, k, vtbf, valid, out, po, pz);
    hipLaunchKernelGGL(combine_kernel, dim3(1024), dim3(256), 0, stream, po, pz, out);
  } else {
    hipLaunchKernelGGL((attn_kernel<1>), dim3(256), dim3(128), 0, stream,
                       q, k, vtbf, valid, out, po, pz);
  }
}

// Round 5
// 134.430 us; speedup vs baseline: 1.0456x; 1.0456x over previous
//
#include <hip/hip_runtime.h>
#include <stdint.h>

#define BB 16
#define NN 2048
#define DD 64
#define BN 64
#define KSTR 72   // K/V LDS row stride (bf16): 144 B rows, 16B-aligned
#define VSTR 72
#define PSTR 40   // P rows: 32 keys + pad -> 80 B, 16B-aligned

typedef __attribute__((ext_vector_type(8))) short short8;
typedef __attribute__((ext_vector_type(16))) float f32x16;

__device__ __forceinline__ unsigned short f2bf(float f) {   // RNE (prep)
  union { float f; uint32_t u; } c; c.f = f;
  uint32_t u = c.u + 0x7fffu + ((c.u >> 16) & 1u);
  return (unsigned short)(u >> 16);
}
__device__ __forceinline__ uint32_t pk2(float a, float b) {  // round-half-up bf16x2
  union { float f; uint32_t u; } x, y; x.f = a; y.f = b;
  return ((x.u + 0x8000u) >> 16) | ((y.u + 0x8000u) & 0xffff0000u);
}

// ---- pre-pass: V fp32 [b][key][d] -> bf16 transposed vt [b][d][key] (verified R2/R4) ----
__global__ __launch_bounds__(256) void prep_kernel(const float* __restrict__ v,
                                                   unsigned short* __restrict__ vt) {
  __shared__ float t[64][65];
  int bid = blockIdx.x, tid = threadIdx.x;
  int b = bid >> 5;
  int k0 = (bid & 31) * 64;
  const float4* src = (const float4*)(v + ((size_t)b * NN + k0) * DD);
#pragma unroll
  for (int i = 0; i < 4; i++) {
    int f4 = tid + i * 256;
    int row = f4 >> 4, c4 = f4 & 15;
    float4 f = src[f4];
    t[row][c4*4+0] = f.x; t[row][c4*4+1] = f.y; t[row][c4*4+2] = f.z; t[row][c4*4+3] = f.w;
  }
  __syncthreads();
  int d = tid >> 2, kg = tid & 3;
  unsigned short* dst = vt + ((size_t)b * DD + d) * NN + k0 + kg * 16;
#pragma unroll
  for (int u = 0; u < 4; u++) {
    ushort4 o4;
    o4.x = f2bf(t[kg*16+u*4+0][d]);
    o4.y = f2bf(t[kg*16+u*4+1][d]);
    o4.z = f2bf(t[kg*16+u*4+2][d]);
    o4.w = f2bf(t[kg*16+u*4+3][d]);
    ((ushort4*)dst)[u] = o4;
  }
}

// ---- main: 32x32x16 MFMA, S^T orientation, 4 waves = (qh,kh), BN=64 ----
template <int NSP>
__global__ __launch_bounds__(256, 4) void attn_kernel(
    const float* __restrict__ q, const float* __restrict__ kin,
    const unsigned short* __restrict__ vtbf, const int* __restrict__ valid,
    float* __restrict__ out, unsigned short* __restrict__ po,
    float* __restrict__ pz)
{
  constexpr int JL = NN / NSP;
  constexpr int IT = JL / BN;

  __shared__ __align__(16) unsigned char smem[28672];
  unsigned short* Klds = (unsigned short*)smem;            // 64 keys x 72   (9216 B)
  unsigned short* Vlds = (unsigned short*)(smem + 9216);   // 64 d    x 72   (9216 B)
  unsigned short* Plds = (unsigned short*)(smem + 18432);  // 4 waves x 32q x 40 (10240 B)

  // XCD swizzle: id&7 = XCD, 2 batches/XCD for K/V L2 residency
  int id = blockIdx.x;
  int b = (id & 7) + 8 * ((id >> 3) & 1);
  int r2 = id >> 4;
  int sp = r2 % NSP;
  int qt = r2 / NSP;
  int i0 = qt * 64;
  int jbase = sp * JL;

  int tid = threadIdx.x;
  int w = tid >> 6, lane = tid & 63;
  int qh = w & 1, kh = w >> 1;        // wave (qh,kh): queries qh*32.., key-half kh
  int q32 = lane & 31, h = lane >> 5;

  int vq = valid[b * NN + i0 + qh * 32 + q32];

  // Q B-fragment: B[col=q32][k=ds*16+h*8+j], scale 0.125 folded, fp32->bf16
  short8 qf[4];
  {
    const float* qp = q + ((size_t)b * NN + i0 + qh * 32 + q32) * DD;
#pragma unroll
    for (int ds = 0; ds < 4; ds++) {
      float4 f0 = *(const float4*)(qp + ds * 16 + h * 8);
      float4 f1 = *(const float4*)(qp + ds * 16 + h * 8 + 4);
      union { short8 v; uint32_t x[4]; } tmp;
      tmp.x[0] = pk2(f0.x * 0.125f, f0.y * 0.125f);
      tmp.x[1] = pk2(f0.z * 0.125f, f0.w * 0.125f);
      tmp.x[2] = pk2(f1.x * 0.125f, f1.y * 0.125f);
      tmp.x[3] = pk2(f1.z * 0.125f, f1.w * 0.125f);
      qf[ds] = tmp.v;
    }
  }

  f32x16 o0 = {}, o1 = {};            // O^T partials: d-tiles 0-31 / 32-63 x 32 queries
  float z = 0.0f;
  unsigned short* pbase = Plds + w * 32 * PSTR;

  // staging: thread -> row tid>>2, 16-col chunk (tid&3)*16
  int srow = tid >> 2, scol = (tid & 3) * 16;
  const float* gk = kin + ((size_t)(b * NN + jbase + srow)) * DD + scol;          // fp32 K
  const unsigned short* gv = vtbf + ((size_t)b * DD + srow) * NN + jbase + scol;  // bf16 Vt

  float4 kr[4]; uint4 vr2[2];
#pragma unroll
  for (int i = 0; i < 4; i++) kr[i] = ((const float4*)gk)[i];
#pragma unroll
  for (int i = 0; i < 2; i++) vr2[i] = ((const uint4*)gv)[i];

  const float CM = 1.0000010f;        // exp(1e-6): masked-key weight (NOT zero)

  for (int it = 0; it < IT; ++it) {
    int jb0 = jbase + it * BN;
    __syncthreads();                  // prior tile fully consumed
#pragma unroll
    for (int s = 0; s < 2; s++) {
      union { uint4 u4; uint32_t x[4]; } kw;
      kw.x[0] = pk2(kr[2*s].x, kr[2*s].y);
      kw.x[1] = pk2(kr[2*s].z, kr[2*s].w);
      kw.x[2] = pk2(kr[2*s+1].x, kr[2*s+1].y);
      kw.x[3] = pk2(kr[2*s+1].z, kr[2*s+1].w);
      *(uint4*)&Klds[srow * KSTR + scol + s * 8] = kw.u4;
      *(uint4*)&Vlds[srow * VSTR + scol + s * 8] = vr2[s];
    }
    if (it + 1 < IT) {                // prefetch next tile
      gk += BN * DD; gv += BN;
#pragma unroll
      for (int i = 0; i < 4; i++) kr[i] = ((const float4*)gk)[i];
#pragma unroll
      for (int i = 0; i < 2; i++) vr2[i] = ((const uint4*)gv)[i];
    }
    __syncthreads();

    // S^T = K . Q^T over this wave's 32-key half
    f32x16 s = {};
#pragma unroll
    for (int ds = 0; ds < 4; ds++) {
      short8 kf = *(const short8*)&Klds[(kh * 32 + q32) * KSTR + ds * 16 + h * 8];
      s = __builtin_amdgcn_mfma_f32_32x32x16_bf16(kf, qf[ds], s, 0, 0, 0);
    }

    // exp + mask; C/D: col=q32(query), key = g*8 + 4h + rr (local), j = jb0+kh*32+key
#pragma unroll
    for (int g = 0; g < 4; g++) {
      float e[4];
#pragma unroll
      for (int rr = 0; rr < 4; rr++) {
        int j = jb0 + kh * 32 + g * 8 + 4 * h + rr;
        float ex = __expf(s[g * 4 + rr]);
        e[rr] = (j < vq) ? ex : CM;
        z += e[rr];
      }
      *(uint2*)&pbase[q32 * PSTR + g * 8 + 4 * h] =
          make_uint2(pk2(e[0], e[1]), pk2(e[2], e[3]));
    }

    __builtin_amdgcn_s_waitcnt(0xc07f);  // lgkmcnt(0): wave-local P RAW

    // O^T += V^T . P^T over the 32-key half (2 k-steps)
#pragma unroll
    for (int ks = 0; ks < 2; ks++) {
      short8 pf  = *(const short8*)&pbase[q32 * PSTR + ks * 16 + h * 8];
      short8 vf0 = *(const short8*)&Vlds[q32 * VSTR + kh * 32 + ks * 16 + h * 8];
      short8 vf1 = *(const short8*)&Vlds[(32 + q32) * VSTR + kh * 32 + ks * 16 + h * 8];
      o0 = __builtin_amdgcn_mfma_f32_32x32x16_bf16(vf0, pf, o0, 0, 0, 0);
      o1 = __builtin_amdgcn_mfma_f32_32x32x16_bf16(vf1, pf, o1, 0, 0, 0);
    }
  }

  z += __shfl_xor(z, 32);             // reduce over h halves

  // cross-wave (kh) reduction through LDS overlay on K/V region
  __syncthreads();
  float* red = (float*)smem;          // 2 x 64 lanes x 33 f32 = 16896 B (fits 18432)
  if (kh == 1) {
    float* rp = red + (qh * 64 + lane) * 33;
#pragma unroll
    for (int r = 0; r < 16; r++) { rp[r] = o0[r]; rp[16 + r] = o1[r]; }
    rp[32] = z;
  }
  __syncthreads();
  if (kh == 0) {
    const float* rp = red + (qh * 64 + lane) * 33;
#pragma unroll
    for (int r = 0; r < 16; r++) { o0[r] += rp[r]; o1[r] += rp[16 + r]; }
    z += rp[32];

    int row = i0 + qh * 32 + q32;

    // lane^32 exchange -> each lane holds 16 CONTIGUOUS d-elems per tile
    // own chunk g: d = t*32 + g*8 + 4h + (0..3)
    float st[2][16];
#pragma unroll
    for (int t = 0; t < 2; t++) {
      const f32x16& ov = t ? o1 : o0;
      float a[4], bx[4];
#pragma unroll
      for (int rr = 0; rr < 4; rr++) {
        a[rr]  = h ? ov[0 * 4 + rr] : ov[2 * 4 + rr];  // send g0 / g2
        bx[rr] = h ? ov[1 * 4 + rr] : ov[3 * 4 + rr];  // send g1 / g3
      }
      float ra[4], rb[4];
#pragma unroll
      for (int rr = 0; rr < 4; rr++) {
        ra[rr] = __shfl_xor(a[rr], 32);
        rb[rr] = __shfl_xor(bx[rr], 32);
      }
      if (h == 0) {
#pragma unroll
        for (int rr = 0; rr < 4; rr++) {
          st[t][rr] = ov[rr]; st[t][4 + rr] = ra[rr];
          st[t][8 + rr] = ov[4 + rr]; st[t][12 + rr] = rb[rr];
        }
      } else {
#pragma unroll
        for (int rr = 0; rr < 4; rr++) {
          st[t][rr] = ra[rr]; st[t][4 + rr] = ov[8 + rr];
          st[t][8 + rr] = rb[rr]; st[t][12 + rr] = ov[12 + rr];
        }
      }
    }

    if (NSP > 1) {
      unsigned short* op = po + ((size_t)((sp * BB + b) * NN) + row) * DD;
#pragma unroll
      for (int t = 0; t < 2; t++) {
        union { uint4 u4[2]; uint32_t x[8]; } pw;
#pragma unroll
        for (int i = 0; i < 8; i++) pw.x[i] = pk2(st[t][2*i], st[t][2*i+1]);
        *(uint4*)&op[t * 32 + h * 16]     = pw.u4[0];
        *(uint4*)&op[t * 32 + h * 16 + 8] = pw.u4[1];
      }
      if (h == 0) pz[(size_t)(sp * BB + b) * NN + row] = z;
    } else {
      float inv = 1.0f / z;
      float* op = out + ((size_t)b * NN + row) * DD;
#pragma unroll
      for (int t = 0; t < 2; t++)
#pragma unroll
        for (int c = 0; c < 4; c++)
          *(float4*)&op[t * 32 + h * 16 + c * 4] =
              make_float4(st[t][c*4]*inv, st[t][c*4+1]*inv, st[t][c*4+2]*inv, st[t][c*4+3]*inv);
    }
  }
}

// ---- combine (2-way): out = (po0+po1)/(z0+z1) (verified R2) ----
__global__ __launch_bounds__(256) void combine_kernel(const unsigned short* __restrict__ po,
                                                      const float* __restrict__ pz,
                                                      float* __restrict__ out) {
  int gid = blockIdx.x * 256 + threadIdx.x;
  size_t base = (size_t)gid * 8;
  int rowz = gid >> 3;
  uint4 a = *(const uint4*)(po + base);
  uint4 c = *(const uint4*)(po + (size_t)BB * NN * DD + base);
  float inv = 1.0f / (pz[rowz] + pz[(size_t)BB * NN + rowz]);
  uint32_t aw[4] = {a.x, a.y, a.z, a.w}, cw[4] = {c.x, c.y, c.z, c.w};
  float r[8];
#pragma unroll
  for (int i = 0; i < 4; i++) {
    float alo = __uint_as_float(aw[i] << 16), ahi = __uint_as_float(aw[i] & 0xffff0000u);
    float clo = __uint_as_float(cw[i] << 16), chi = __uint_as_float(cw[i] & 0xffff0000u);
    r[2*i]   = (alo + clo) * inv;
    r[2*i+1] = (ahi + chi) * inv;
  }
  float4* op = (float4*)(out + base);
  op[0] = make_float4(r[0], r[1], r[2], r[3]);
  op[1] = make_float4(r[4], r[5], r[6], r[7]);
}

extern "C" void kernel_launch(void* const* d_in, const int* in_sizes, int n_in,
                              void* d_out, int out_size, void* d_ws, size_t ws_size,
                              hipStream_t stream) {
  const float* q = (const float*)d_in[0];
  const float* k = (const float*)d_in[1];
  const float* v = (const float*)d_in[2];
  const int* valid = (const int*)d_in[3];
  float* out = (float*)d_out;

  unsigned short* vtbf = (unsigned short*)d_ws;                  // 4 MB
  unsigned short* po   = vtbf + (size_t)BB * NN * DD;            // 2 x 4 MB bf16 partials
  float* pz = (float*)(po + (size_t)2 * BB * NN * DD);           // 2 x 128 KB

  size_t need = (size_t)BB * NN * DD * 2                         // vtbf
              + (size_t)2 * BB * NN * DD * 2                     // po
              + (size_t)2 * BB * NN * 4;                         // pz

  hipLaunchKernelGGL(prep_kernel, dim3(BB * (NN / 64)), dim3(256), 0, stream, v, vtbf);
  if (ws_size >= need) {
    hipLaunchKernelGGL((attn_kernel<2>), dim3(16 * 32 * 2), dim3(256), 0, stream,
                       q, k, vtbf, valid, out, po, pz);
    hipLaunchKernelGGL(combine_kernel, dim3(1024), dim3(256), 0, stream, po, pz, out);
  } else {
    hipLaunchKernelGGL((attn_kernel<1>), dim3(16 * 32), dim3(256), 0, stream,
                       q, k, vtbf, valid, out, po, pz);
  }
}

// Round 6
// 115.826 us; speedup vs baseline: 1.2135x; 1.1606x over previous
//
#include <hip/hip_runtime.h>
#include <hip/hip_bf16.h>
#include <stdint.h>

#define BB 16
#define NN 2048
#define DD 64
#define BM 64
#define BN 64
#define KSTR 72   // K/Vt LDS row stride in bf16 elems (144 B: 16B-aligned)
#define PSTR 72   // P LDS row stride

typedef __attribute__((ext_vector_type(8))) short short8;
typedef __attribute__((ext_vector_type(4))) float f32x4;

__device__ __forceinline__ unsigned short f2bf(float f) {   // RNE (pre-pass)
  union { float f; uint32_t u; } c; c.f = f;
  uint32_t u = c.u + 0x7fffu + ((c.u >> 16) & 1u);
  return (unsigned short)(u >> 16);
}
__device__ __forceinline__ uint32_t pkrn(float a, float b) { // packed f32x2 -> bf16x2
  union { __hip_bfloat162 h; uint32_t u; } c;
  c.h = __float22bfloat162_rn(make_float2(a, b));
  return c.u;
}

// ---- fused pre-pass: blocks [0,2048): K fp32->bf16 copy; [2048,2560): V transpose ----
__global__ __launch_bounds__(256) void prep_kernel(const float* __restrict__ k,
                                                   const float* __restrict__ v,
                                                   unsigned short* __restrict__ kbf,
                                                   unsigned short* __restrict__ vt) {
  __shared__ float t[64][65];
  int id = blockIdx.x, tid = threadIdx.x;
  if (id < 2048) {
    int i = id * 256 + tid;
    float4 f = ((const float4*)k)[i];
    ushort4 o;
    o.x = f2bf(f.x); o.y = f2bf(f.y); o.z = f2bf(f.z); o.w = f2bf(f.w);
    ((ushort4*)kbf)[i] = o;
  } else {
    int bid = id - 2048;
    int b = bid >> 5;
    int k0 = (bid & 31) * 64;
    const float4* src = (const float4*)(v + ((size_t)b * NN + k0) * DD);
#pragma unroll
    for (int i = 0; i < 4; i++) {
      int f4 = tid + i * 256;
      int row = f4 >> 4, c4 = f4 & 15;
      float4 f = src[f4];
      t[row][c4*4+0] = f.x; t[row][c4*4+1] = f.y; t[row][c4*4+2] = f.z; t[row][c4*4+3] = f.w;
    }
    __syncthreads();
    int d = tid >> 2, kg = tid & 3;
    unsigned short* dst = vt + ((size_t)b * DD + d) * NN + k0 + kg * 16;
#pragma unroll
    for (int u = 0; u < 4; u++) {
      ushort4 o;
      o.x = f2bf(t[kg*16+u*4+0][d]);
      o.y = f2bf(t[kg*16+u*4+1][d]);
      o.z = f2bf(t[kg*16+u*4+2][d]);
      o.w = f2bf(t[kg*16+u*4+3][d]);
      ((ushort4*)dst)[u] = o;
    }
  }
}

// ---- main flash-attention kernel (R2-verified structure), split-K template ----
template <int NS>
__global__ __launch_bounds__(256, 4) void attn_kernel(
    const float* __restrict__ q, const unsigned short* __restrict__ kbf,
    const unsigned short* __restrict__ vtbf, const int* __restrict__ valid,
    float* __restrict__ out, unsigned short* __restrict__ po,
    float* __restrict__ pz)
{
  constexpr int JLEN = NN / NS;
  constexpr int ITERS = JLEN / BN;

  __shared__ __align__(16) unsigned short Klds[BN * KSTR];
  __shared__ __align__(16) unsigned short Vlds[DD * KSTR];
  __shared__ __align__(16) unsigned short Plds[4 * 16 * PSTR];
  __shared__ int vld[BM];

  // decode with XCD swizzle: id&7 = XCD; 2 batches/XCD for L2 K/V residency
  int id = blockIdx.x;
  int b = (id & 7) + 8 * ((id >> 3) & 1);
  int rest = id >> 4;                 // [0, 32*NS)
  int sp = rest % NS;
  int qt = rest / NS;
  int i0 = qt * BM;
  int jbase = sp * JLEN;

  int tid = threadIdx.x;
  int w = tid >> 6;                   // wave 0..3: queries i0 + w*16 .. +15
  int lane = tid & 63;
  int m = lane & 15;
  int quad = lane >> 4;

  if (tid < BM) vld[tid] = valid[b * NN + i0 + tid];

  // Q fragment (B-operand layout: lane m holds Q[m][quad*8+j]), scale 0.125 folded
  short8 qf[2];
  {
    const float* qp = q + ((size_t)b * NN + (i0 + w * 16 + m)) * DD;
#pragma unroll
    for (int s = 0; s < 2; s++) {
      float4 f0 = *(const float4*)(qp + s * 32 + quad * 8);
      float4 f1 = *(const float4*)(qp + s * 32 + quad * 8 + 4);
      union { short8 v; uint32_t x[4]; } tmp;
      tmp.x[0] = pkrn(f0.x * 0.125f, f0.y * 0.125f);
      tmp.x[1] = pkrn(f0.z * 0.125f, f0.w * 0.125f);
      tmp.x[2] = pkrn(f1.x * 0.125f, f1.y * 0.125f);
      tmp.x[3] = pkrn(f1.z * 0.125f, f1.w * 0.125f);
      qf[s] = tmp.v;
    }
  }

  __syncthreads();
  int vq = vld[w * 16 + m];           // valid[] for this lane's query m

  f32x4 o[4] = {{0,0,0,0},{0,0,0,0},{0,0,0,0},{0,0,0,0}};
  float z = 0.0f;
  unsigned short* pbase = Plds + w * 16 * PSTR;

  // staging: thread t loads 16 contiguous bf16 of row t>>2 at col (t&3)*16
  int srow = tid >> 2, scol = (tid & 3) * 16;
  const unsigned short* gk = kbf + ((size_t)(b * NN + jbase + srow)) * DD + scol;
  const unsigned short* gv = vtbf + ((size_t)b * DD + srow) * NN + jbase + scol;

  uint4 ka = *(const uint4*)gk, kb2 = *(const uint4*)(gk + 8);
  uint4 va = *(const uint4*)gv, vb2 = *(const uint4*)(gv + 8);

  for (int it = 0; it < ITERS; ++it) {
    int j0 = jbase + it * BN;
    __syncthreads();   // prior tile consumed
    *(uint4*)&Klds[srow * KSTR + scol]     = ka;
    *(uint4*)&Klds[srow * KSTR + scol + 8] = kb2;
    *(uint4*)&Vlds[srow * KSTR + scol]     = va;
    *(uint4*)&Vlds[srow * KSTR + scol + 8] = vb2;
    if (it + 1 < ITERS) {   // prefetch next tile; latency overlaps compute below
      gk += BN * DD; gv += BN;
      ka = *(const uint4*)gk; kb2 = *(const uint4*)(gk + 8);
      va = *(const uint4*)gv; vb2 = *(const uint4*)(gv + 8);
    }
    __syncthreads();

    // S^T = K . Q^T : lane supplies A=K[c*16+m][d], B=Q[m][d]; D: row=key, col=query
    f32x4 s[4] = {{0,0,0,0},{0,0,0,0},{0,0,0,0},{0,0,0,0}};
#pragma unroll
    for (int c = 0; c < 4; c++) {
#pragma unroll
      for (int ss = 0; ss < 2; ss++) {
        short8 kf = *(const short8*)&Klds[(c * 16 + m) * KSTR + ss * 32 + quad * 8];
        s[c] = __builtin_amdgcn_mfma_f32_16x16x32_bf16(kf, qf[ss], s[c], 0, 0, 0);
      }
    }

    // P[query m][key]: masked score = 1e-6 (weight ~1, NOT zero)
#pragma unroll
    for (int c = 0; c < 4; c++) {
      float e[4];
#pragma unroll
      for (int rr = 0; rr < 4; rr++) {
        int j = j0 + c * 16 + quad * 4 + rr;
        float arg = (j < vq) ? s[c][rr] : 1.0e-6f;
        e[rr] = __expf(arg);
      }
      z += (e[0] + e[1]) + (e[2] + e[3]);
      *(uint2*)&pbase[m * PSTR + c * 16 + quad * 4] =
          make_uint2(pkrn(e[0], e[1]), pkrn(e[2], e[3]));
    }

    __builtin_amdgcn_s_waitcnt(0xc07f);  // lgkmcnt(0): wave-local P RAW

    // O^T = V^T . P^T : A=Vt[t*16+m][key], B=P[m][key]
#pragma unroll
    for (int ss = 0; ss < 2; ss++) {
      short8 pf = *(const short8*)&pbase[m * PSTR + ss * 32 + quad * 8];
#pragma unroll
      for (int t = 0; t < 4; t++) {
        short8 vf = *(const short8*)&Vlds[(t * 16 + m) * KSTR + ss * 32 + quad * 8];
        o[t] = __builtin_amdgcn_mfma_f32_16x16x32_bf16(vf, pf, o[t], 0, 0, 0);
      }
    }
  }

  // z: sum over the 4 quads holding the same query m
  z += __shfl_xor(z, 16);
  z += __shfl_xor(z, 32);

  if (NS > 1) {
    int row = i0 + w * 16 + m;
    unsigned short* op = po + ((size_t)((sp * BB + b) * NN) + row) * DD;
#pragma unroll
    for (int t = 0; t < 4; t++)
      *(uint2*)&op[t * 16 + quad * 4] = make_uint2(pkrn(o[t][0], o[t][1]),
                                                   pkrn(o[t][2], o[t][3]));
    if (quad == 0) pz[(size_t)(sp * BB + b) * NN + row] = z;
  } else {
    float inv = 1.0f / z;
    int row = i0 + w * 16 + m;
    float* op = out + ((size_t)b * NN + row) * DD;
#pragma unroll
    for (int t = 0; t < 4; t++)
      *(float4*)&op[t * 16 + quad * 4] =
          make_float4(o[t][0]*inv, o[t][1]*inv, o[t][2]*inv, o[t][3]*inv);
  }
}

// ---- combine: out = sum_sp po / sum_sp z ----
template <int NS>
__global__ __launch_bounds__(256) void combine_kernel(const unsigned short* __restrict__ po,
                                                      const float* __restrict__ pz,
                                                      float* __restrict__ out) {
  int gid = blockIdx.x * 256 + threadIdx.x;   // 262144 threads x 8 elems
  size_t base = (size_t)gid * 8;
  int rowz = gid >> 3;
  float r[8] = {0,0,0,0,0,0,0,0};
  float zs = 0.0f;
#pragma unroll
  for (int sp = 0; sp < NS; sp++) {
    uint4 a = *(const uint4*)(po + (size_t)sp * BB * NN * DD + base);
    zs += pz[(size_t)sp * BB * NN + rowz];
    uint32_t aw[4] = {a.x, a.y, a.z, a.w};
#pragma unroll
    for (int i = 0; i < 4; i++) {
      r[2*i]   += __uint_as_float(aw[i] << 16);
      r[2*i+1] += __uint_as_float(aw[i] & 0xffff0000u);
    }
  }
  float inv = 1.0f / zs;
  float4* op = (float4*)(out + base);
  op[0] = make_float4(r[0]*inv, r[1]*inv, r[2]*inv, r[3]*inv);
  op[1] = make_float4(r[4]*inv, r[5]*inv, r[6]*inv, r[7]*inv);
}

extern "C" void kernel_launch(void* const* d_in, const int* in_sizes, int n_in,
                              void* d_out, int out_size, void* d_ws, size_t ws_size,
                              hipStream_t stream) {
  const float* q = (const float*)d_in[0];
  const float* k = (const float*)d_in[1];
  const float* v = (const float*)d_in[2];
  const int* valid = (const int*)d_in[3];
  float* out = (float*)d_out;

  unsigned short* kbf  = (unsigned short*)d_ws;                    // 4 MB
  unsigned short* vtbf = kbf + (size_t)BB * NN * DD;               // 4 MB
  unsigned short* po   = vtbf + (size_t)BB * NN * DD;              // NS x 4 MB bf16 partials
  float* pz4 = (float*)(po + (size_t)4 * BB * NN * DD);
  float* pz2 = (float*)(po + (size_t)2 * BB * NN * DD);

  size_t fixed = (size_t)2 * BB * NN * DD * 2;  // kbf + vtbf
  size_t need4 = fixed + (size_t)4 * BB * NN * DD * 2 + (size_t)4 * BB * NN * 4;
  size_t need2 = fixed + (size_t)2 * BB * NN * DD * 2 + (size_t)2 * BB * NN * 4;

  hipLaunchKernelGGL(prep_kernel, dim3(2560), dim3(256), 0, stream, k, v, kbf, vtbf);
  if (ws_size >= need4) {
    hipLaunchKernelGGL((attn_kernel<4>), dim3(16 * 32 * 4), dim3(256), 0, stream,
                       q, kbf, vtbf, valid, out, po, pz4);
    hipLaunchKernelGGL((combine_kernel<4>), dim3(1024), dim3(256), 0, stream, po, pz4, out);
  } else if (ws_size >= need2) {
    hipLaunchKernelGGL((attn_kernel<2>), dim3(16 * 32 * 2), dim3(256), 0, stream,
                       q, kbf, vtbf, valid, out, po, pz2);
    hipLaunchKernelGGL((combine_kernel<2>), dim3(1024), dim3(256), 0, stream, po, pz2, out);
  } else {
    hipLaunchKernelGGL((attn_kernel<1>), dim3(16 * 32), dim3(256), 0, stream,
                       q, kbf, vtbf, valid, out, po, pz2);
  }
}